// Round 3
// baseline (25242.360 us; speedup 1.0000x reference)
//
#include <hip/hip_runtime.h>
#include <stdint.h>

// R3: fix R2's spill regression. 8 waves/block (512 thr), 1 co-tile per wave:
// afr 112->56 VGPR, acc 56->28. Persistent blocks + double-buffered LDS kept;
// register-staged async pipeline REMOVED (it spilled: FETCH 95->490MB in R2).
// Occupancy 2/SIMD -> 4/SIMD does the latency hiding instead.

typedef __attribute__((ext_vector_type(8))) short short8;
typedef __attribute__((ext_vector_type(4))) float float4v;

#define NPIX 240
#define PIXSTRIDE 68   // shorts per pixel (64 ci + 4 pad) = 136 B: 8B-aligned rows,
                       // word-stride 34 == 2 mod 32 -> 2-way (free) conflicts

// ws layout: [0, 57344): wsA frag-ordered bf16 weights (4ct*14ks*64lane*8)
//            [57344, 58304): map (240 int, last 15 = -1)
//            [58304, 58980): out-mask (169 float)
#define MAP_OFF   57344
#define OM_OFF    58304

__device__ __forceinline__ unsigned short f2bf(float f) {
    union { float f; unsigned u; } v; v.f = f;
    unsigned r = v.u + 0x7FFFu + ((v.u >> 16) & 1u);   // RNE
    return (unsigned short)(r >> 16);
}

__global__ void hex_prep_kernel(const float* __restrict__ w,
                                unsigned short* __restrict__ wsA,
                                int* __restrict__ map,
                                float* __restrict__ om) {
    const int gid = blockIdx.x * blockDim.x + threadIdx.x;
    const int nthr = gridDim.x * blockDim.x;
    const int ti_tab[7] = {0,0,1,1,1,2,2};
    const int tj_tab[7] = {0,1,0,1,2,1,2};
    // fragment-ordered weights: item = (ct*14 + ks)*64 + lane, 8 bf16 each
    for (int item = gid; item < 4*14*64; item += nthr) {
        int lane = item & 63;
        int ks   = (item >> 6) % 14;
        int ct   = (item >> 6) / 14;
        int co = ct*16 + (lane & 15);
        int k0 = ks*32 + (lane >> 4)*8;
        unsigned short vals[8];
        #pragma unroll
        for (int j = 0; j < 8; ++j) {
            int k = k0 + j;
            int tap = k >> 6, ci = k & 63;
            vals[j] = f2bf(w[(co*64 + ci)*9 + ti_tab[tap]*3 + tj_tab[tap]]);
        }
        for (int j = 0; j < 8; ++j) wsA[item*8 + j] = vals[j];
    }
    if (gid == 0) {
        // hex padding source map: replay reference copies on indices
        int m[225];
        for (int r = 0; r < 15; ++r)
            for (int c = 0; c < 15; ++c)
                m[r*15+c] = (r>=1 && r<=13 && c>=1 && c<=13) ? (r-1)*13 + (c-1) : -1;
        #define M(r,c) m[(r)*15+(c)]
        for (int t = 0; t < 7; ++t) M(0,1+t)    = M(12,7+t);
        for (int r = 0; r < 3; ++r) M(r,8+r)    = M(6+r,2+r);
        for (int r = 0; r < 4; ++r) M(3+r,10+r) = M(9+r,4+r);
        for (int r = 0; r < 3; ++r) M(7+r,13)   = M(1+r,1);
        for (int r = 0; r < 3; ++r) M(10+r,14)  = M(4+r,2);
        for (int r = 0; r < 8; ++r) M(13,7+r)   = M(1,1+r);
        for (int r = 0; r < 4; ++r) M(9+r,3+r)  = M(3+r,9+r);
        for (int r = 0; r < 3; ++r) M(6+r,1+r)  = M(r,7+r);
        for (int r = 0; r < 2; ++r) M(4+r,1)    = M(10+r,13);
        for (int r = 0; r < 4; ++r) M(r,0)      = M(6+r,12);
        #undef M
        for (int i = 0; i < 225; ++i) map[i] = m[i];
        for (int i = 225; i < 240; ++i) map[i] = -1;
        // output mask
        float o[169];
        for (int i = 0; i < 169; ++i) o[i] = 1.f;
        for (int i = 0; i < 5; ++i) for (int j = 8+i; j < 13; ++j) o[i*13+j] = 0.f;
        for (int i = 0; i < 4; ++i) o[(2+i)*13 + 9+i] = 0.f;
        for (int i = 6; i < 9; ++i) o[i*13 + 12] = 0.f;
        for (int i = 0; i < 6; ++i) for (int j = 0; j <= i; ++j) o[(6+i)*13 + j] = 0.f;
        for (int i = 0; i < 3; ++i) o[(5+i)*13 + i] = 0.f;
        o[3*13 + 0] = 0.f; o[4*13 + 0] = 0.f;
        for (int i = 0; i < 169; ++i) om[i] = o[i];
    }
}

// 8 waves: wave wv -> (ct = wv&3, nth = wv>>2) for compute;
//          (pg = wv&3, h = wv>>2) for staging (pixel group, ci half).
// Per image: stage(next -> buf^1) [sync, 16-float chunks], MFMA(buf),
// epilogue, one barrier. Persistent constants loaded once per block.
__global__ __launch_bounds__(512, 4) void hexconv_kernel(
        const float* __restrict__ x, const float* __restrict__ bias,
        const unsigned short* __restrict__ wsA, const int* __restrict__ map,
        const float* __restrict__ om, float* __restrict__ out,
        int B, int ipb) {
    __shared__ unsigned short Xs[2][NPIX * PIXSTRIDE];   // 2 x 32640 B
    const int tid = threadIdx.x;
    const int lane = tid & 63, wv = tid >> 6;
    const int lr = lane & 15, lq = lane >> 4;
    const int ct  = wv & 3;
    const int nth = wv >> 2;

    const int b0   = blockIdx.x * ipb;
    const int bend = (b0 + ipb < B) ? (b0 + ipb) : B;
    if (b0 >= bend) return;

    // ---- per-block constants (ONCE) ----
    short8 afr[14];                       // 56 VGPR
    #pragma unroll
    for (int ks = 0; ks < 14; ++ks)
        afr[ks] = *(const short8*)(wsA + (size_t)((ct*14 + ks)*64 + lane)*8);

    const int pg = wv & 3, h = wv >> 2;
    const int p  = lane + 64*pg;
    const bool pact = (p < NPIX);
    const int sp = pact ? map[p] : -1;

    float biasv[4];
    #pragma unroll
    for (int r = 0; r < 4; ++r)
        biasv[r] = bias[ct*16 + lq*4 + r];

    // epilogue geometry: col p15 = nt*16 + lr -> (y, xc)
    int ep_off[7]; float ep_om[7]; unsigned okmask = 0;
    #pragma unroll
    for (int j = 0; j < 7; ++j) {
        int nt = nth*7 + j;
        int p15 = nt*16 + lr;
        int y = p15 / 15, xc = p15 % 15;
        bool ok = (nt < 13) && (xc < 13) && (y < 13);
        ep_off[j] = ok ? (y*13 + xc) : 0;
        ep_om[j]  = ok ? om[y*13 + xc] : 0.f;
        if (ok) okmask |= (1u << j);
    }

    // ---- synchronous stage: 2 chunks of 16 floats (caps live regs) ----
    auto stage = [&](int sel, const float* __restrict__ xb) {
        if (pact) {
            #pragma unroll
            for (int half = 0; half < 2; ++half) {
                float lv[16];
                #pragma unroll
                for (int k = 0; k < 16; ++k) {
                    int ci = h*32 + half*16 + k;
                    lv[k] = (sp >= 0) ? xb[ci*169 + sp] : 0.f;
                }
                #pragma unroll
                for (int q = 0; q < 4; ++q) {
                    uint64_t pk = (uint64_t)f2bf(lv[4*q])
                                | ((uint64_t)f2bf(lv[4*q+1]) << 16)
                                | ((uint64_t)f2bf(lv[4*q+2]) << 32)
                                | ((uint64_t)f2bf(lv[4*q+3]) << 48);
                    *(uint64_t*)&Xs[sel][p*PIXSTRIDE + h*32 + half*16 + q*4] = pk;
                }
            }
        }
    };

    const int offs[7] = {0,1,15,16,17,31,32};   // ti*15+tj for the 7 hex taps

    // ---- prologue: stage first image into buffer 0 ----
    stage(0, x + (size_t)b0 * (64*169));
    __syncthreads();

    int cur = 0;
    for (int b = b0; b < bend; ++b) {
        // stage next image into the other buffer (sync; TLP hides latency)
        if (b + 1 < bend)
            stage(cur ^ 1, x + (size_t)(b + 1) * (64*169));

        // ---- MFMA on current buffer ----
        float4v acc[7];
        #pragma unroll
        for (int j = 0; j < 7; ++j)
            acc[j] = float4v{0.f, 0.f, 0.f, 0.f};

        #pragma unroll
        for (int ks = 0; ks < 14; ++ks) {
            const int tap = ks >> 1;             // k-step never straddles a tap
            const int cib = (ks & 1)*32 + lq*8;
            #pragma unroll
            for (int j = 0; j < 7; ++j) {
                int nt = nth*7 + j;
                if (nt < 13) {
                    int pixb = nt*16 + lr + offs[tap];
                    const unsigned short* ptr = &Xs[cur][pixb*PIXSTRIDE + cib];
                    union { short8 v; uint64_t q[2]; } u;
                    u.q[0] = *(const uint64_t*)ptr;
                    u.q[1] = *(const uint64_t*)(ptr + 4);
                    acc[j] = __builtin_amdgcn_mfma_f32_16x16x32_bf16(
                        afr[ks], u.v, acc[j], 0, 0, 0);
                }
            }
        }

        // ---- epilogue before barrier (acc dies here; stores drain at barrier)
        #pragma unroll
        for (int j = 0; j < 7; ++j) {
            if (!((okmask >> j) & 1u)) continue;
            size_t obase = (size_t)b * (64*169) + ep_off[j];
            float omv = ep_om[j];
            #pragma unroll
            for (int r = 0; r < 4; ++r) {
                int co = ct*16 + lq*4 + r;
                out[obase + (size_t)co*169] = (acc[j][r] + biasv[r]) * omv;
            }
        }

        __syncthreads();                          // one barrier per image
        cur ^= 1;
    }
}

extern "C" void kernel_launch(void* const* d_in, const int* in_sizes, int n_in,
                              void* d_out, int out_size, void* d_ws, size_t ws_size,
                              hipStream_t stream) {
    const float* x    = (const float*)d_in[0];
    const float* w    = (const float*)d_in[1];
    const float* bias = (const float*)d_in[2];
    float* out = (float*)d_out;

    unsigned short* wsA = (unsigned short*)d_ws;
    int*   map = (int*)((char*)d_ws + MAP_OFF);
    float* om  = (float*)((char*)d_ws + OM_OFF);

    hex_prep_kernel<<<16, 256, 0, stream>>>(w, wsA, map, om);

    int B = in_sizes[0] / (64 * 169);   // 4096 images
    int nblk = 512;                     // 2 blocks/CU (LDS-capped), persistent
    if (nblk > B) nblk = B;
    int ipb = (B + nblk - 1) / nblk;
    hexconv_kernel<<<nblk, 512, 0, stream>>>(x, bias, wsA, map, om, out, B, ipb);
}

// Round 4
// 1221.099 us; speedup vs baseline: 20.6718x; 20.6718x over previous
//
#include <hip/hip_runtime.h>
#include <stdint.h>

// R4: back to R0's verified register structure (92 arch VGPR, no spills).
// Changes vs R0, both register-neutral:
//   1) __launch_bounds__(256,3): 3 blocks/CU (budget 170 > R0's ~156 used)
//   2) ipb=4 persistence-lite: afr/map/bias/epilogue hoisted over 4 images,
//      single Xs buffer, two barriers per image.
// R2/R3's register-staged pipeline and 8-wave split are dead: both spilled
// (arch budget is ~half of 512/waves_per_EU due to the unified-file
// accum_offset split; R3 got 64 arch regs and wrote 112 GB of scratch).

typedef __attribute__((ext_vector_type(8))) short short8;
typedef __attribute__((ext_vector_type(4))) float float4v;

#define NPIX 240
#define PIXSTRIDE 68   // shorts per pixel (64 ci + 4 pad) = 136 B: 8B-aligned rows,
                       // word-stride 34 == 2 mod 32 -> 2-way (free) conflicts

// ws layout: [0, 57344): wsA frag-ordered bf16 weights (4ct*14ks*64lane*8)
//            [57344, 58304): map (240 int, last 15 = -1)
//            [58304, 58980): out-mask (169 float)
#define MAP_OFF   57344
#define OM_OFF    58304

__device__ __forceinline__ unsigned short f2bf(float f) {
    union { float f; unsigned u; } v; v.f = f;
    unsigned r = v.u + 0x7FFFu + ((v.u >> 16) & 1u);   // RNE
    return (unsigned short)(r >> 16);
}

__global__ void hex_prep_kernel(const float* __restrict__ w,
                                unsigned short* __restrict__ wsA,
                                int* __restrict__ map,
                                float* __restrict__ om) {
    const int gid = blockIdx.x * blockDim.x + threadIdx.x;
    const int nthr = gridDim.x * blockDim.x;
    const int ti_tab[7] = {0,0,1,1,1,2,2};
    const int tj_tab[7] = {0,1,0,1,2,1,2};
    // fragment-ordered weights: item = (ct*14 + ks)*64 + lane, 8 bf16 each
    for (int item = gid; item < 4*14*64; item += nthr) {
        int lane = item & 63;
        int ks   = (item >> 6) % 14;
        int ct   = (item >> 6) / 14;
        int co = ct*16 + (lane & 15);
        int k0 = ks*32 + (lane >> 4)*8;
        unsigned short vals[8];
        #pragma unroll
        for (int j = 0; j < 8; ++j) {
            int k = k0 + j;
            int tap = k >> 6, ci = k & 63;
            vals[j] = f2bf(w[(co*64 + ci)*9 + ti_tab[tap]*3 + tj_tab[tap]]);
        }
        for (int j = 0; j < 8; ++j) wsA[item*8 + j] = vals[j];
    }
    if (gid == 0) {
        // hex padding source map: replay reference copies on indices
        int m[225];
        for (int r = 0; r < 15; ++r)
            for (int c = 0; c < 15; ++c)
                m[r*15+c] = (r>=1 && r<=13 && c>=1 && c<=13) ? (r-1)*13 + (c-1) : -1;
        #define M(r,c) m[(r)*15+(c)]
        for (int t = 0; t < 7; ++t) M(0,1+t)    = M(12,7+t);
        for (int r = 0; r < 3; ++r) M(r,8+r)    = M(6+r,2+r);
        for (int r = 0; r < 4; ++r) M(3+r,10+r) = M(9+r,4+r);
        for (int r = 0; r < 3; ++r) M(7+r,13)   = M(1+r,1);
        for (int r = 0; r < 3; ++r) M(10+r,14)  = M(4+r,2);
        for (int r = 0; r < 8; ++r) M(13,7+r)   = M(1,1+r);
        for (int r = 0; r < 4; ++r) M(9+r,3+r)  = M(3+r,9+r);
        for (int r = 0; r < 3; ++r) M(6+r,1+r)  = M(r,7+r);
        for (int r = 0; r < 2; ++r) M(4+r,1)    = M(10+r,13);
        for (int r = 0; r < 4; ++r) M(r,0)      = M(6+r,12);
        #undef M
        for (int i = 0; i < 225; ++i) map[i] = m[i];
        for (int i = 225; i < 240; ++i) map[i] = -1;
        // output mask
        float o[169];
        for (int i = 0; i < 169; ++i) o[i] = 1.f;
        for (int i = 0; i < 5; ++i) for (int j = 8+i; j < 13; ++j) o[i*13+j] = 0.f;
        for (int i = 0; i < 4; ++i) o[(2+i)*13 + 9+i] = 0.f;
        for (int i = 6; i < 9; ++i) o[i*13 + 12] = 0.f;
        for (int i = 0; i < 6; ++i) for (int j = 0; j <= i; ++j) o[(6+i)*13 + j] = 0.f;
        for (int i = 0; i < 3; ++i) o[(5+i)*13 + i] = 0.f;
        o[3*13 + 0] = 0.f; o[4*13 + 0] = 0.f;
        for (int i = 0; i < 169; ++i) om[i] = o[i];
    }
}

// wave w: ctp = w&1 owns co-tiles {2ctp, 2ctp+1}; nth = w>>1 owns nt = nth*7 + j.
// R0 structure, looped over ipb images with constants hoisted.
__global__ __launch_bounds__(256, 3) void hexconv_kernel(
        const float* __restrict__ x, const float* __restrict__ bias,
        const unsigned short* __restrict__ wsA, const int* __restrict__ map,
        const float* __restrict__ om, float* __restrict__ out,
        int B, int ipb) {
    __shared__ unsigned short Xs[NPIX * PIXSTRIDE];   // 32640 B, single buffer
    const int tid = threadIdx.x;
    const int lane = tid & 63, wv = tid >> 6;
    const int lr = lane & 15, lq = lane >> 4;
    const int ctp = wv & 1;
    const int nth = wv >> 1;

    const int b0   = blockIdx.x * ipb;
    const int bend = (b0 + ipb < B) ? (b0 + ipb) : B;
    if (b0 >= bend) return;

    // ---- per-block constants (loaded ONCE, reused for ipb images) ----
    short8 afr[2][14];                   // 112 arch VGPR, same as R0
    #pragma unroll
    for (int c = 0; c < 2; ++c) {
        const int ct = ctp*2 + c;
        #pragma unroll
        for (int ks = 0; ks < 14; ++ks)
            afr[c][ks] = *(const short8*)(wsA + (size_t)((ct*14 + ks)*64 + lane)*8);
    }
    int sp[4];
    #pragma unroll
    for (int pi = 0; pi < 4; ++pi) {
        int pix = lane + 64*pi;
        sp[pi] = (pix < NPIX) ? map[pix] : -1;
    }
    float biasv[2][4];
    #pragma unroll
    for (int c = 0; c < 2; ++c)
        #pragma unroll
        for (int r = 0; r < 4; ++r)
            biasv[c][r] = bias[(ctp*2 + c)*16 + lq*4 + r];
    int ep_off[7]; float ep_om[7]; unsigned okmask = 0;
    #pragma unroll
    for (int j = 0; j < 7; ++j) {
        int nt = nth*7 + j;
        int p15 = nt*16 + lr;
        int y = p15 / 15, xc = p15 % 15;
        bool ok = (nt < 13) && (xc < 13) && (y < 13);
        ep_off[j] = ok ? (y*13 + xc) : 0;
        ep_om[j]  = ok ? om[y*13 + xc] : 0.f;
        if (ok) okmask |= (1u << j);
    }

    const int offs[7] = {0,1,15,16,17,31,32};   // ti*15+tj for the 7 hex taps

    for (int b = b0; b < bend; ++b) {
        const float* xb = x + (size_t)b * (64*169);

        // ---- staging: lane <-> pixel, wave <-> ci-block (R0 pattern) ----
        #pragma unroll
        for (int pi = 0; pi < 4; ++pi) {
            int pix = lane + 64*pi;
            if (pix < NPIX) {
                const int s = sp[pi];
                unsigned short vals[16];
                #pragma unroll
                for (int cj = 0; cj < 16; ++cj) {
                    int ci = wv*16 + cj;
                    float v = (s >= 0) ? xb[ci*169 + s] : 0.f;
                    vals[cj] = f2bf(v);
                }
                #pragma unroll
                for (int q = 0; q < 4; ++q) {
                    uint64_t pk = (uint64_t)vals[4*q]
                                | ((uint64_t)vals[4*q+1] << 16)
                                | ((uint64_t)vals[4*q+2] << 32)
                                | ((uint64_t)vals[4*q+3] << 48);
                    *(uint64_t*)&Xs[pix*PIXSTRIDE + wv*16 + q*4] = pk;
                }
            }
        }
        __syncthreads();

        // ---- main loop: pure LDS + MFMA (R0 pattern) ----
        float4v acc[2][7];
        #pragma unroll
        for (int c = 0; c < 2; ++c)
            #pragma unroll
            for (int j = 0; j < 7; ++j)
                acc[c][j] = float4v{0.f, 0.f, 0.f, 0.f};

        #pragma unroll
        for (int ks = 0; ks < 14; ++ks) {
            const int tap = ks >> 1;                 // k-step never straddles a tap
            const int cib = (ks & 1)*32 + lq*8;
            #pragma unroll
            for (int j = 0; j < 7; ++j) {
                int nt = nth*7 + j;
                if (nt < 13) {
                    int pixb = nt*16 + lr + offs[tap];
                    const unsigned short* p = &Xs[pixb*PIXSTRIDE + cib];
                    union { short8 v; uint64_t q[2]; } u;
                    u.q[0] = *(const uint64_t*)p;
                    u.q[1] = *(const uint64_t*)(p + 4);
                    #pragma unroll
                    for (int c = 0; c < 2; ++c)
                        acc[c][j] = __builtin_amdgcn_mfma_f32_16x16x32_bf16(
                            afr[c][ks], u.v, acc[c][j], 0, 0, 0);
                }
            }
        }

        // ---- epilogue (hoisted geometry) ----
        #pragma unroll
        for (int j = 0; j < 7; ++j) {
            if (!((okmask >> j) & 1u)) continue;
            size_t obase = (size_t)b * (64*169) + ep_off[j];
            float omv = ep_om[j];
            #pragma unroll
            for (int c = 0; c < 2; ++c) {
                #pragma unroll
                for (int r = 0; r < 4; ++r) {
                    int co = (ctp*2 + c)*16 + lq*4 + r;
                    out[obase + (size_t)co*169] = (acc[c][j][r] + biasv[c][r]) * omv;
                }
            }
        }

        __syncthreads();   // Xs write-after-read guard for next image's stage
    }
}

extern "C" void kernel_launch(void* const* d_in, const int* in_sizes, int n_in,
                              void* d_out, int out_size, void* d_ws, size_t ws_size,
                              hipStream_t stream) {
    const float* x    = (const float*)d_in[0];
    const float* w    = (const float*)d_in[1];
    const float* bias = (const float*)d_in[2];
    float* out = (float*)d_out;

    unsigned short* wsA = (unsigned short*)d_ws;
    int*   map = (int*)((char*)d_ws + MAP_OFF);
    float* om  = (float*)((char*)d_ws + OM_OFF);

    hex_prep_kernel<<<16, 256, 0, stream>>>(w, wsA, map, om);

    int B = in_sizes[0] / (64 * 169);   // 4096 images
    int ipb = 4;                        // images per block
    int nblk = (B + ipb - 1) / ipb;     // 1024 blocks: 4 slots/CU, 3 resident
    hexconv_kernel<<<nblk, 256, 0, stream>>>(x, bias, wsA, map, om, out, B, ipb);
}

// Round 5
// 600.052 us; speedup vs baseline: 42.0670x; 2.0350x over previous
//
#include <hip/hip_runtime.h>
#include <stdint.h>

// R5: structural register fix + pipeline, at the verified (256,2) budget.
// Calibrated model from R2/R3/R4 failures: (256,2) => 256 unified VGPR+AGPR
// per wave; R0 sits at ~250 (afr 112 + acc 56 + ~90 working) -- saturated.
// Change: 1 co-tile per wave (ct=wv): afr 112->56, acc 56->52 (-60 regs),
// paying 2x LDS B-reads (LDS pipe was ~20% busy -- cheap). Headroom spent on:
//   - persistent 512 blocks x 8 images, LDS double-buffer (2x32640B, 2/CU)
//   - 4-chunk interleave: issue 16 loads (b+1) -> MFMA quarter (~900 cyc,
//     covers HBM latency) -> convert+ds_write -> next chunk. 16 floats max.
//   - epilogue AFTER barrier (syncthreads drains vmcnt(0); post-barrier
//     stores get a whole image of MFMA to retire under).
// Est. ~220/256 regs. Spill tripwire: FETCH>250MB or WRITE>220MB/dispatch.

typedef __attribute__((ext_vector_type(8))) short short8;
typedef __attribute__((ext_vector_type(4))) float float4v;

#define NPIX 240
#define PIXSTRIDE 68   // shorts per pixel (64 ci + 4 pad) = 136 B: 8B-aligned rows,
                       // word-stride 34 == 2 mod 32 -> 2-way (free) conflicts

// ws layout: [0, 57344): wsA frag-ordered bf16 weights (4ct*14ks*64lane*8)
//            [57344, 58304): map (240 int, last 15 = -1)
//            [58304, 58980): out-mask (169 float)
#define MAP_OFF   57344
#define OM_OFF    58304

__device__ __forceinline__ unsigned short f2bf(float f) {
    union { float f; unsigned u; } v; v.f = f;
    unsigned r = v.u + 0x7FFFu + ((v.u >> 16) & 1u);   // RNE
    return (unsigned short)(r >> 16);
}

__global__ void hex_prep_kernel(const float* __restrict__ w,
                                unsigned short* __restrict__ wsA,
                                int* __restrict__ map,
                                float* __restrict__ om) {
    const int gid = blockIdx.x * blockDim.x + threadIdx.x;
    const int nthr = gridDim.x * blockDim.x;
    const int ti_tab[7] = {0,0,1,1,1,2,2};
    const int tj_tab[7] = {0,1,0,1,2,1,2};
    // fragment-ordered weights: item = (ct*14 + ks)*64 + lane, 8 bf16 each
    for (int item = gid; item < 4*14*64; item += nthr) {
        int lane = item & 63;
        int ks   = (item >> 6) % 14;
        int ct   = (item >> 6) / 14;
        int co = ct*16 + (lane & 15);
        int k0 = ks*32 + (lane >> 4)*8;
        unsigned short vals[8];
        #pragma unroll
        for (int j = 0; j < 8; ++j) {
            int k = k0 + j;
            int tap = k >> 6, ci = k & 63;
            vals[j] = f2bf(w[(co*64 + ci)*9 + ti_tab[tap]*3 + tj_tab[tap]]);
        }
        for (int j = 0; j < 8; ++j) wsA[item*8 + j] = vals[j];
    }
    if (gid == 0) {
        // hex padding source map: replay reference copies on indices
        int m[225];
        for (int r = 0; r < 15; ++r)
            for (int c = 0; c < 15; ++c)
                m[r*15+c] = (r>=1 && r<=13 && c>=1 && c<=13) ? (r-1)*13 + (c-1) : -1;
        #define M(r,c) m[(r)*15+(c)]
        for (int t = 0; t < 7; ++t) M(0,1+t)    = M(12,7+t);
        for (int r = 0; r < 3; ++r) M(r,8+r)    = M(6+r,2+r);
        for (int r = 0; r < 4; ++r) M(3+r,10+r) = M(9+r,4+r);
        for (int r = 0; r < 3; ++r) M(7+r,13)   = M(1+r,1);
        for (int r = 0; r < 3; ++r) M(10+r,14)  = M(4+r,2);
        for (int r = 0; r < 8; ++r) M(13,7+r)   = M(1,1+r);
        for (int r = 0; r < 4; ++r) M(9+r,3+r)  = M(3+r,9+r);
        for (int r = 0; r < 3; ++r) M(6+r,1+r)  = M(r,7+r);
        for (int r = 0; r < 2; ++r) M(4+r,1)    = M(10+r,13);
        for (int r = 0; r < 4; ++r) M(r,0)      = M(6+r,12);
        #undef M
        for (int i = 0; i < 225; ++i) map[i] = m[i];
        for (int i = 225; i < 240; ++i) map[i] = -1;
        // output mask
        float o[169];
        for (int i = 0; i < 169; ++i) o[i] = 1.f;
        for (int i = 0; i < 5; ++i) for (int j = 8+i; j < 13; ++j) o[i*13+j] = 0.f;
        for (int i = 0; i < 4; ++i) o[(2+i)*13 + 9+i] = 0.f;
        for (int i = 6; i < 9; ++i) o[i*13 + 12] = 0.f;
        for (int i = 0; i < 6; ++i) for (int j = 0; j <= i; ++j) o[(6+i)*13 + j] = 0.f;
        for (int i = 0; i < 3; ++i) o[(5+i)*13 + i] = 0.f;
        o[3*13 + 0] = 0.f; o[4*13 + 0] = 0.f;
        for (int i = 0; i < 169; ++i) om[i] = o[i];
    }
}

// wave wv owns co-tile ct = wv (16 co's); covers ALL 13 nt-tiles.
// Staging mapping unchanged from R0: thread (lane, wv) stages pixels
// lane+64*pi (pi=0..3) for ci range wv*16..wv*16+15, in 4 chunks of 16 floats.
__global__ __launch_bounds__(256, 2) void hexconv_kernel(
        const float* __restrict__ x, const float* __restrict__ bias,
        const unsigned short* __restrict__ wsA, const int* __restrict__ map,
        const float* __restrict__ om, float* __restrict__ out,
        int B, int ipb) {
    __shared__ unsigned short Xs[2][NPIX * PIXSTRIDE];   // 2 x 32640 B = 65280 B
    const int tid = threadIdx.x;
    const int lane = tid & 63, wv = tid >> 6;
    const int lr = lane & 15, lq = lane >> 4;
    const int ct = wv;                      // 1 co-tile per wave

    const int b0   = blockIdx.x * ipb;
    const int bend = (b0 + ipb < B) ? (b0 + ipb) : B;
    if (b0 >= bend) return;

    // ---- per-block constants (ONCE per 8 images) ----
    short8 afr[14];                          // 56 regs (1 ct only)
    #pragma unroll
    for (int ks = 0; ks < 14; ++ks)
        afr[ks] = *(const short8*)(wsA + (size_t)((ct*14 + ks)*64 + lane)*8);

    int sp[4];
    #pragma unroll
    for (int pi = 0; pi < 4; ++pi) {
        int pix = lane + 64*pi;
        sp[pi] = (pix < NPIX) ? map[pix] : -1;
    }
    float biasv[4];
    #pragma unroll
    for (int r = 0; r < 4; ++r)
        biasv[r] = bias[ct*16 + lq*4 + r];

    // epilogue geometry for all 13 nt (j = nt directly now)
    int ep_off[13]; float ep_om[13]; unsigned okmask = 0;
    #pragma unroll
    for (int j = 0; j < 13; ++j) {
        int p15 = j*16 + lr;
        int y = p15 / 15, xc = p15 % 15;
        bool ok = (xc < 13) && (y < 13);
        ep_off[j] = ok ? (y*13 + xc) : 0;
        ep_om[j]  = ok ? om[y*13 + xc] : 0.f;
        if (ok) okmask |= (1u << j);
    }

    // ---- chunked staging: 16 floats in flight max ----
    auto issue_chunk = [&](const float* __restrict__ xb, int pi, float (&lv)[16]) {
        int pix = lane + 64*pi;
        if (pix < NPIX) {
            const int s = sp[pi];
            #pragma unroll
            for (int cj = 0; cj < 16; ++cj)
                lv[cj] = (s >= 0) ? xb[(wv*16 + cj)*169 + s] : 0.f;
        }
    };
    auto cwrite_chunk = [&](int sel, int pi, const float (&lv)[16]) {
        int pix = lane + 64*pi;
        if (pix < NPIX) {
            #pragma unroll
            for (int q = 0; q < 4; ++q) {
                uint64_t pk = (uint64_t)f2bf(lv[4*q])
                            | ((uint64_t)f2bf(lv[4*q+1]) << 16)
                            | ((uint64_t)f2bf(lv[4*q+2]) << 32)
                            | ((uint64_t)f2bf(lv[4*q+3]) << 48);
                *(uint64_t*)&Xs[sel][pix*PIXSTRIDE + wv*16 + q*4] = pk;
            }
        }
    };

    const int offs[7] = {0,1,15,16,17,31,32};   // ti*15+tj for the 7 hex taps

    // MFMA over ks range [KA,KB) for all 13 nt into acc[13]
#define MFMA_Q(SEL, KA, KB) do {                                              \
    _Pragma("unroll")                                                         \
    for (int ks = (KA); ks < (KB); ++ks) {                                    \
        const int tap = ks >> 1;               /* k-step never straddles */   \
        const int cib = (ks & 1)*32 + lq*8;                                   \
        _Pragma("unroll")                                                     \
        for (int j = 0; j < 13; ++j) {                                        \
            int pixb = j*16 + lr + offs[tap];                                 \
            const unsigned short* p = &Xs[SEL][pixb*PIXSTRIDE + cib];         \
            union { short8 v; uint64_t q[2]; } u;                             \
            u.q[0] = *(const uint64_t*)p;                                     \
            u.q[1] = *(const uint64_t*)(p + 4);                               \
            acc[j] = __builtin_amdgcn_mfma_f32_16x16x32_bf16(                 \
                afr[ks], u.v, acc[j], 0, 0, 0);                               \
        }                                                                     \
    }                                                                         \
} while (0)

    // ---- prologue: stage first image into buffer 0 ----
    {
        const float* xb = x + (size_t)b0 * (64*169);
        float lv[16];
        #pragma unroll
        for (int pi = 0; pi < 4; ++pi) {
            issue_chunk(xb, pi, lv);
            cwrite_chunk(0, pi, lv);
        }
    }
    __syncthreads();

    int cur = 0;
    for (int b = b0; b < bend; ++b) {
        const bool havenext = (b + 1 < bend);
        const float* xbn = x + (size_t)(b + 1) * (64*169);

        float4v acc[13];
        #pragma unroll
        for (int j = 0; j < 13; ++j)
            acc[j] = float4v{0.f, 0.f, 0.f, 0.f};

        float lv[16];
        if (havenext) issue_chunk(xbn, 0, lv);     // fly under quarter 0
        MFMA_Q(cur, 0, 4);
        if (havenext) { cwrite_chunk(cur ^ 1, 0, lv); issue_chunk(xbn, 1, lv); }
        MFMA_Q(cur, 4, 8);
        if (havenext) { cwrite_chunk(cur ^ 1, 1, lv); issue_chunk(xbn, 2, lv); }
        MFMA_Q(cur, 8, 11);
        if (havenext) { cwrite_chunk(cur ^ 1, 2, lv); issue_chunk(xbn, 3, lv); }
        MFMA_Q(cur, 11, 14);
        if (havenext) cwrite_chunk(cur ^ 1, 3, lv);

        __syncthreads();   // drains ds_writes; buf^1 ready, buf consumed

        // ---- epilogue AFTER barrier: stores retire under next image's MFMA
        #pragma unroll
        for (int j = 0; j < 13; ++j) {
            if (!((okmask >> j) & 1u)) continue;
            size_t obase = (size_t)b * (64*169) + ep_off[j];
            float omv = ep_om[j];
            #pragma unroll
            for (int r = 0; r < 4; ++r) {
                int co = ct*16 + lq*4 + r;
                out[obase + (size_t)co*169] = (acc[j][r] + biasv[r]) * omv;
            }
        }

        cur ^= 1;
    }
#undef MFMA_Q
}

extern "C" void kernel_launch(void* const* d_in, const int* in_sizes, int n_in,
                              void* d_out, int out_size, void* d_ws, size_t ws_size,
                              hipStream_t stream) {
    const float* x    = (const float*)d_in[0];
    const float* w    = (const float*)d_in[1];
    const float* bias = (const float*)d_in[2];
    float* out = (float*)d_out;

    unsigned short* wsA = (unsigned short*)d_ws;
    int*   map = (int*)((char*)d_ws + MAP_OFF);
    float* om  = (float*)((char*)d_ws + OM_OFF);

    hex_prep_kernel<<<16, 256, 0, stream>>>(w, wsA, map, om);

    int B = in_sizes[0] / (64 * 169);   // 4096 images
    int nblk = 512;                     // persistent: 2 blocks/CU resident
    if (nblk > B) nblk = B;
    int ipb = (B + nblk - 1) / nblk;    // 8 images per block
    hexconv_kernel<<<nblk, 256, 0, stream>>>(x, bias, wsA, map, om, out, B, ipb);
}

// Round 6
// 579.529 us; speedup vs baseline: 43.5567x; 1.0354x over previous
//
#include <hip/hip_runtime.h>
#include <stdint.h>

// R6: R0's EXACT register frame (92 arch VGPR, proven spill-free) with the
// per-image barrier moved off the stage->MFMA critical path:
//   per image: stage(b+1 -> buf^1) ; MFMA(buf) ; epilogue(b) ; barrier
// Double-buffered Xs (2x32640B), persistent blocks (512 x 8 images) hoisting
// afr/map. NO register-carried loads across the MFMA region -- R2/R4/R5 all
// spilled doing that (scheduler hoisting inflates live sets far beyond hand
// counts; estimates were wrong 3/3). Staging code is R0-verbatim, transient.

typedef __attribute__((ext_vector_type(8))) short short8;
typedef __attribute__((ext_vector_type(4))) float float4v;

#define NPIX 240
#define PIXSTRIDE 68   // shorts per pixel (64 ci + 4 pad) = 136 B: 8B-aligned rows,
                       // word-stride 34 == 2 mod 32 -> 2-way (free) conflicts

// ws layout: [0, 57344): wsA frag-ordered bf16 weights (4ct*14ks*64lane*8)
//            [57344, 58304): map (240 int, last 15 = -1)
//            [58304, 58980): out-mask (169 float)
#define MAP_OFF   57344
#define OM_OFF    58304

__device__ __forceinline__ unsigned short f2bf(float f) {
    union { float f; unsigned u; } v; v.f = f;
    unsigned r = v.u + 0x7FFFu + ((v.u >> 16) & 1u);   // RNE
    return (unsigned short)(r >> 16);
}

__global__ void hex_prep_kernel(const float* __restrict__ w,
                                unsigned short* __restrict__ wsA,
                                int* __restrict__ map,
                                float* __restrict__ om) {
    const int gid = blockIdx.x * blockDim.x + threadIdx.x;
    const int nthr = gridDim.x * blockDim.x;
    const int ti_tab[7] = {0,0,1,1,1,2,2};
    const int tj_tab[7] = {0,1,0,1,2,1,2};
    // fragment-ordered weights: item = (ct*14 + ks)*64 + lane, 8 bf16 each
    for (int item = gid; item < 4*14*64; item += nthr) {
        int lane = item & 63;
        int ks   = (item >> 6) % 14;
        int ct   = (item >> 6) / 14;
        int co = ct*16 + (lane & 15);
        int k0 = ks*32 + (lane >> 4)*8;
        unsigned short vals[8];
        #pragma unroll
        for (int j = 0; j < 8; ++j) {
            int k = k0 + j;
            int tap = k >> 6, ci = k & 63;
            vals[j] = f2bf(w[(co*64 + ci)*9 + ti_tab[tap]*3 + tj_tab[tap]]);
        }
        for (int j = 0; j < 8; ++j) wsA[item*8 + j] = vals[j];
    }
    if (gid == 0) {
        // hex padding source map: replay reference copies on indices
        int m[225];
        for (int r = 0; r < 15; ++r)
            for (int c = 0; c < 15; ++c)
                m[r*15+c] = (r>=1 && r<=13 && c>=1 && c<=13) ? (r-1)*13 + (c-1) : -1;
        #define M(r,c) m[(r)*15+(c)]
        for (int t = 0; t < 7; ++t) M(0,1+t)    = M(12,7+t);
        for (int r = 0; r < 3; ++r) M(r,8+r)    = M(6+r,2+r);
        for (int r = 0; r < 4; ++r) M(3+r,10+r) = M(9+r,4+r);
        for (int r = 0; r < 3; ++r) M(7+r,13)   = M(1+r,1);
        for (int r = 0; r < 3; ++r) M(10+r,14)  = M(4+r,2);
        for (int r = 0; r < 8; ++r) M(13,7+r)   = M(1,1+r);
        for (int r = 0; r < 4; ++r) M(9+r,3+r)  = M(3+r,9+r);
        for (int r = 0; r < 3; ++r) M(6+r,1+r)  = M(r,7+r);
        for (int r = 0; r < 2; ++r) M(4+r,1)    = M(10+r,13);
        for (int r = 0; r < 4; ++r) M(r,0)      = M(6+r,12);
        #undef M
        for (int i = 0; i < 225; ++i) map[i] = m[i];
        for (int i = 225; i < 240; ++i) map[i] = -1;
        // output mask
        float o[169];
        for (int i = 0; i < 169; ++i) o[i] = 1.f;
        for (int i = 0; i < 5; ++i) for (int j = 8+i; j < 13; ++j) o[i*13+j] = 0.f;
        for (int i = 0; i < 4; ++i) o[(2+i)*13 + 9+i] = 0.f;
        for (int i = 6; i < 9; ++i) o[i*13 + 12] = 0.f;
        for (int i = 0; i < 6; ++i) for (int j = 0; j <= i; ++j) o[(6+i)*13 + j] = 0.f;
        for (int i = 0; i < 3; ++i) o[(5+i)*13 + i] = 0.f;
        o[3*13 + 0] = 0.f; o[4*13 + 0] = 0.f;
        for (int i = 0; i < 169; ++i) om[i] = o[i];
    }
}

// wave w: ctp = w&1 owns co-tiles {2ctp, 2ctp+1}; nth = w>>1 owns nt = nth*7 + j.
// R0's wave layout, staging pattern, MFMA loop, and epilogue -- verbatim.
__global__ __launch_bounds__(256, 2) void hexconv_kernel(
        const float* __restrict__ x, const float* __restrict__ bias,
        const unsigned short* __restrict__ wsA, const int* __restrict__ map,
        const float* __restrict__ om, float* __restrict__ out,
        int B, int ipb) {
    __shared__ unsigned short Xs[2][NPIX * PIXSTRIDE];   // 65280 B, 2 blocks/CU
    const int tid = threadIdx.x;
    const int lane = tid & 63, wv = tid >> 6;
    const int lr = lane & 15, lq = lane >> 4;
    const int ctp = wv & 1;
    const int nth = wv >> 1;

    const int b0   = blockIdx.x * ipb;
    const int bend = (b0 + ipb < B) ? (b0 + ipb) : B;
    if (b0 >= bend) return;

    // ---- per-block constants (ONCE per ipb images) ----
    short8 afr[2][14];                   // 112 regs, R0's exact frame
    #pragma unroll
    for (int c = 0; c < 2; ++c) {
        const int ct = ctp*2 + c;
        #pragma unroll
        for (int ks = 0; ks < 14; ++ks)
            afr[c][ks] = *(const short8*)(wsA + (size_t)((ct*14 + ks)*64 + lane)*8);
    }
    int sp[4];
    #pragma unroll
    for (int pi = 0; pi < 4; ++pi) {
        int pix = lane + 64*pi;
        sp[pi] = (pix < NPIX) ? map[pix] : -1;
    }

    // ---- staging: R0-verbatim body, parameterized by buffer ----
    auto stage = [&](int sel, const float* __restrict__ xb) {
        #pragma unroll
        for (int pi = 0; pi < 4; ++pi) {
            int pix = lane + 64*pi;
            if (pix < NPIX) {
                const int s = sp[pi];
                unsigned short vals[16];
                #pragma unroll
                for (int cj = 0; cj < 16; ++cj) {
                    int ci = wv*16 + cj;
                    float v = (s >= 0) ? xb[ci*169 + s] : 0.f;
                    vals[cj] = f2bf(v);
                }
                #pragma unroll
                for (int q = 0; q < 4; ++q) {
                    uint64_t pk = (uint64_t)vals[4*q]
                                | ((uint64_t)vals[4*q+1] << 16)
                                | ((uint64_t)vals[4*q+2] << 32)
                                | ((uint64_t)vals[4*q+3] << 48);
                    *(uint64_t*)&Xs[sel][pix*PIXSTRIDE + wv*16 + q*4] = pk;
                }
            }
        }
    };

    const int offs[7] = {0,1,15,16,17,31,32};   // ti*15+tj for the 7 hex taps

    // ---- prologue: stage first image into buffer 0 ----
    stage(0, x + (size_t)b0 * (64*169));
    __syncthreads();

    int cur = 0;
    for (int b = b0; b < bend; ++b) {
        // stage NEXT image into the other buffer -- no barrier before MFMA:
        // different buffer; waves that finish early proceed straight to MFMA.
        if (b + 1 < bend)
            stage(cur ^ 1, x + (size_t)(b + 1) * (64*169));

        // ---- main loop: pure LDS + MFMA (R0 pattern) ----
        float4v acc[2][7];
        #pragma unroll
        for (int c = 0; c < 2; ++c)
            #pragma unroll
            for (int j = 0; j < 7; ++j)
                acc[c][j] = float4v{0.f, 0.f, 0.f, 0.f};

        #pragma unroll
        for (int ks = 0; ks < 14; ++ks) {
            const int tap = ks >> 1;                 // k-step never straddles a tap
            const int cib = (ks & 1)*32 + lq*8;
            #pragma unroll
            for (int j = 0; j < 7; ++j) {
                int nt = nth*7 + j;
                if (nt < 13) {
                    int pixb = nt*16 + lr + offs[tap];
                    const unsigned short* p = &Xs[cur][pixb*PIXSTRIDE + cib];
                    union { short8 v; uint64_t q[2]; } u;
                    u.q[0] = *(const uint64_t*)p;
                    u.q[1] = *(const uint64_t*)(p + 4);
                    #pragma unroll
                    for (int c = 0; c < 2; ++c)
                        acc[c][j] = __builtin_amdgcn_mfma_f32_16x16x32_bf16(
                            afr[c][ks], u.v, acc[c][j], 0, 0, 0);
                }
            }
        }

        // ---- epilogue: R0-verbatim (inline geometry, om/bias loads) ----
        #pragma unroll
        for (int j = 0; j < 7; ++j) {
            int nt = nth*7 + j;
            if (nt >= 13) continue;
            int p15 = nt*16 + lr;
            int y = p15 / 15, xc = p15 % 15;
            if (xc >= 13 || y >= 13) continue;
            float omv = om[y*13 + xc];
            size_t obase = (size_t)b * (64*169) + y*13 + xc;
            #pragma unroll
            for (int c = 0; c < 2; ++c) {
                int ct = ctp*2 + c;
                #pragma unroll
                for (int r = 0; r < 4; ++r) {
                    int co = ct*16 + lq*4 + r;
                    out[obase + (size_t)co*169] = (acc[c][j][r] + bias[co]) * omv;
                }
            }
        }

        __syncthreads();   // single barrier/image: publishes buf^1, retires buf
        cur ^= 1;
    }
}

extern "C" void kernel_launch(void* const* d_in, const int* in_sizes, int n_in,
                              void* d_out, int out_size, void* d_ws, size_t ws_size,
                              hipStream_t stream) {
    const float* x    = (const float*)d_in[0];
    const float* w    = (const float*)d_in[1];
    const float* bias = (const float*)d_in[2];
    float* out = (float*)d_out;

    unsigned short* wsA = (unsigned short*)d_ws;
    int*   map = (int*)((char*)d_ws + MAP_OFF);
    float* om  = (float*)((char*)d_ws + OM_OFF);

    hex_prep_kernel<<<16, 256, 0, stream>>>(w, wsA, map, om);

    int B = in_sizes[0] / (64 * 169);   // 4096 images
    int nblk = 512;                     // persistent: 2 blocks/CU resident
    if (nblk > B) nblk = B;
    int ipb = (B + nblk - 1) / nblk;    // 8 images per block
    hexconv_kernel<<<nblk, 256, 0, stream>>>(x, bias, wsA, map, om, out, B, ipb);
}